// Round 5
// baseline (97.234 us; speedup 1.0000x reference)
//
#include <hip/hip_runtime.h>

// Problem constants (B=4, N=2048 fixed by the reference setup)
#define BB 4
#define NN 2048
#define NPTS (BB * NN)                          // 8192 points
#define PSTR 20                                 // packed floats per point (5 x float4)
#define TS 128                                  // tile size
#define TT (NN / TS)                            // 16 tiles per batch
#define NPAIRS (TT * (TT + 1) / 2)              // 136 unordered tile pairs (incl. diag)
#define MSPL 8                                  // m-splits per tile pair
#define MCH (TS / MSPL)                         // 16 m-points per block
#define JOBS_PER_B (NPAIRS * MSPL)              // 1088
#define NJOBS (JOBS_PER_B * BB)                 // 4352 blocks
#define BLK 128                                 // 2 waves per block
// weight 2 for every surviving (m<n) pair folded into the final scale
#define SCALE (2.0f / ((float)BB * (float)NN * (float)NN))

// d_ws layout
#define WS_COUNTER_OFF 0
#define WS_PART_OFF    256
#define WS_PACK_OFF    (1 << 20)
#define WS_NEEDED      (WS_PACK_OFF + NPTS * PSTR * 4)

__device__ __forceinline__ void quat_to_R(float qw, float qx, float qy, float qz, float* R) {
    R[0] = 1.f - 2.f * (qy * qy + qz * qz);
    R[1] = 2.f * (qx * qy - qz * qw);
    R[2] = 2.f * (qx * qz + qy * qw);
    R[3] = 2.f * (qx * qy + qz * qw);
    R[4] = 1.f - 2.f * (qx * qx + qz * qz);
    R[5] = 2.f * (qy * qz - qx * qw);
    R[6] = 2.f * (qx * qz - qy * qw);
    R[7] = 2.f * (qy * qz + qx * qw);
    R[8] = 1.f - 2.f * (qx * qx + qy * qy);
}

// Pack per-point struct: {x,y,z,sx | sy,sz,vx,vy | vz,R0,R1,R2 | R3,R4,R5,R6 | R7,R8,0,0}
__global__ __launch_bounds__(256) void pack_kernel(
    const float* __restrict__ xyz, const float* __restrict__ scales,
    const float* __restrict__ rot, const float* __restrict__ vel,
    float* __restrict__ pk)
{
    const int i = blockIdx.x * 256 + threadIdx.x;
    if (i >= NPTS) return;
    const size_t i3 = 3 * (size_t)i;
    const float4 q = *reinterpret_cast<const float4*>(rot + 4 * (size_t)i);
    float R[9];
    quat_to_R(q.x, q.y, q.z, q.w, R);
    float4* o = reinterpret_cast<float4*>(pk + PSTR * (size_t)i);
    o[0] = make_float4(xyz[i3], xyz[i3 + 1], xyz[i3 + 2], scales[i3]);
    o[1] = make_float4(scales[i3 + 1], scales[i3 + 2], vel[i3], vel[i3 + 1]);
    o[2] = make_float4(vel[i3 + 2], R[0], R[1], R[2]);
    o[3] = make_float4(R[3], R[4], R[5], R[6]);
    o[4] = make_float4(R[7], R[8], 0.f, 0.f);
}

// Lower-triangle (m<n) pair sum, weight 2 in SCALE.
// Block = (batch, tile-pair, m-split). 128 threads = 128 n-rows (ROWS=1).
// m-side: 16 points, read per-iteration with WAVE-UNIFORM addresses from the
// packed buffer (scalarizable to s_load; no LDS, no __syncthreads in loop).
template <bool ATOMIC>
__global__ __launch_bounds__(BLK, 6) void pair_kernel(
    const float* __restrict__ pk,
    float* __restrict__ partials, unsigned int* __restrict__ counter,
    float* __restrict__ outp)
{
    __shared__ float wsum[2];
    __shared__ int lastflag;

    const int tid = threadIdx.x;
    const int jid = blockIdx.x;
    const int b   = jid / JOBS_PER_B;
    const int rem = jid % JOBS_PER_B;
    const int p   = rem / MSPL;     // triangular tile-pair index
    const int mc  = rem % MSPL;     // m-split

    // decode p -> (ti >= tj)
    int ti = 0;
    while ((ti + 1) * (ti + 2) / 2 <= p) ++ti;
    const int tj = p - ti * (ti + 1) / 2;
    const bool diag = (ti == tj);

    const int n      = ti * TS + tid;
    const int m_base = tj * TS + mc * MCH;

    // ---- own n-row from packed buffer (5 x float4) ----
    const float4* np4 = reinterpret_cast<const float4*>(pk + PSTR * (size_t)(b * NN + n));
    const float4 n0 = np4[0], n1 = np4[1], n2 = np4[2], n3 = np4[3], n4 = np4[4];
    const float px = n0.x, py = n0.y, pz = n0.z;
    const float sx = n0.w, sy = n1.x, sz = n1.y;
    const float vx = n1.z, vy = n1.w, vz = n2.x;
    const float Rn0 = n2.y, Rn1 = n2.z, Rn2 = n2.w;
    const float Rn3 = n3.x, Rn4 = n3.y, Rn5 = n3.z;
    const float Rn6 = n3.w, Rn7 = n4.x, Rn8 = n4.y;

    float acc = 0.f;
    const float4* mp4 = reinterpret_cast<const float4*>(pk + PSTR * (size_t)(b * NN + m_base));

    auto inner = [&](bool isDiag) {
        #pragma unroll 4
        for (int j = 0; j < MCH; ++j) {
            // wave-uniform m-side loads (L1/SMEM broadcast)
            const float4 c0 = mp4[5 * j + 0];
            const float4 c1 = mp4[5 * j + 1];
            const float4 c2 = mp4[5 * j + 2];
            const float4 c3 = mp4[5 * j + 3];
            const float4 c4 = mp4[5 * j + 4];
            const float dx = px - c0.x, dy = py - c0.y, dz = pz - c0.z;
            const float d2 = fmaf(dx, dx, fmaf(dy, dy, fmaf(dz, dz, 1e-8f)));
            const float rinv = __builtin_amdgcn_rsqf(d2);
            // r_dir(n,m): (diff^T R_n) scaled by s_m
            const float a0 = fmaf(dx, Rn0, fmaf(dy, Rn3, dz * Rn6)) * c0.w;
            const float a1 = fmaf(dx, Rn1, fmaf(dy, Rn4, dz * Rn7)) * c1.x;
            const float a2 = fmaf(dx, Rn2, fmaf(dy, Rn5, dz * Rn8)) * c1.y;
            const float qa = __builtin_amdgcn_sqrtf(fmaf(a0, a0, fmaf(a1, a1, a2 * a2)));
            // r_dir(m,n): (diff^T R_m) scaled by s_n (sign dies in the square)
            const float b0 = fmaf(dx, c2.y, fmaf(dy, c3.x, dz * c3.w)) * sx;
            const float b1 = fmaf(dx, c2.z, fmaf(dy, c3.y, dz * c4.x)) * sy;
            const float b2 = fmaf(dx, c2.w, fmaf(dy, c3.z, dz * c4.y)) * sz;
            const float qb = __builtin_amdgcn_sqrtf(fmaf(b0, b0, fmaf(b1, b1, b2 * b2)));
            // overlap = rinv * relu(qa + qb - d2)
            const float ww = fmaxf(qa + qb - d2, 0.f);
            const float ov = ww * rinv;
            const float rc = __builtin_amdgcn_rcpf(fmaf(0.1f, ov, 1.f));
            // v_approach = (v_n - v_m).diff * rinv ; ramp = relu(-v_approach)
            const float vdot = fmaf(vx - c1.z, dx, fmaf(vy - c1.w, dy, (vz - c2.x) * dz));
            const float ramp = fmaxf(-vdot * rinv, 0.f);
            // t = spec + 0.1*ov*ramp = ov * (ov*rc + 0.1*ramp)
            float t = ov * fmaf(ov, rc, 0.1f * ramp);
            if (isDiag && !(m_base + j < n)) t = 0.f;   // diag tiles: keep m<n only
            acc += t;
        }
    };
    if (diag) inner(true); else inner(false);

    // ---- block reduction (2 waves) ----
    #pragma unroll
    for (int off = 32; off > 0; off >>= 1)
        acc += __shfl_down(acc, off, 64);
    if ((tid & 63) == 0) wsum[tid >> 6] = acc;
    __syncthreads();

    if (ATOMIC) {
        if (tid == 0) atomicAdd(outp, (wsum[0] + wsum[1]) * SCALE);
        return;
    }

    if (tid == 0) {
        partials[jid] = wsum[0] + wsum[1];
        __threadfence();                               // release
        const unsigned int done = atomicAdd(counter, 1u);
        lastflag = (done == (unsigned int)(NJOBS - 1));
    }
    __syncthreads();

    if (lastflag) {
        __threadfence();                               // acquire
        const float4* p4 = reinterpret_cast<const float4*>(partials);
        float s = 0.f;
        for (int i = tid; i < NJOBS / 4; i += BLK) {
            const float4 v = p4[i];
            s += v.x + v.y + v.z + v.w;
        }
        #pragma unroll
        for (int off = 32; off > 0; off >>= 1)
            s += __shfl_down(s, off, 64);
        if ((tid & 63) == 0) wsum[tid >> 6] = s;
        __syncthreads();
        if (tid == 0) outp[0] = (wsum[0] + wsum[1]) * SCALE;
    }
}

extern "C" void kernel_launch(void* const* d_in, const int* in_sizes, int n_in,
                              void* d_out, int out_size, void* d_ws, size_t ws_size,
                              hipStream_t stream)
{
    const float* xyz    = (const float*)d_in[0];
    const float* scales = (const float*)d_in[1];
    const float* rot    = (const float*)d_in[2];
    const float* vel    = (const float*)d_in[3];
    float* out = (float*)d_out;

    unsigned int* counter = (unsigned int*)((char*)d_ws + WS_COUNTER_OFF);
    float* partials       = (float*)((char*)d_ws + WS_PART_OFF);
    float* pk             = (float*)((char*)d_ws + WS_PACK_OFF);

    pack_kernel<<<(NPTS + 255) / 256, 256, 0, stream>>>(xyz, scales, rot, vel, pk);

    if (ws_size >= WS_NEEDED) {
        hipMemsetAsync(counter, 0, sizeof(unsigned int), stream);   // graph-safe
        pair_kernel<false><<<NJOBS, BLK, 0, stream>>>(pk, partials, counter, out);
    } else {
        hipMemsetAsync(d_out, 0, sizeof(float), stream);
        pair_kernel<true><<<NJOBS, BLK, 0, stream>>>(pk, nullptr, nullptr, out);
    }
}